// Round 2
// baseline (605.362 us; speedup 1.0000x reference)
//
#include <hip/hip_runtime.h>
#include <hip/hip_bf16.h>
#include <stdint.h>

#define TOKENS 8192
#define DIN 4096
#define DOUT 4096
#define RNK 16
#define LORA_SCALE 2.0f

typedef __attribute__((ext_vector_type(8))) __bf16 bf16x8;
typedef __attribute__((ext_vector_type(4))) float f32x4;

__device__ __forceinline__ unsigned short f2bf(float f) {
    union { float f; unsigned int u; } v; v.f = f;
    unsigned int u = v.u;
    unsigned int r = (u + 0x7fffu + ((u >> 16) & 1u)) >> 16;  // RNE
    return (unsigned short)r;
}

__device__ __forceinline__ void async_copy16(const void* g, void* l) {
    __builtin_amdgcn_global_load_lds(
        (const __attribute__((address_space(1))) void*)g,
        (__attribute__((address_space(3))) void*)l,
        16, 0, 0);
}

// ---------------- kernel 1: cast x (fp32) -> bf16 ----------------
__global__ void cast_x_kernel(const float4* __restrict__ x, ushort4* __restrict__ xb) {
    int i = blockIdx.x * blockDim.x + threadIdx.x;
    float4 v = x[i];
    ushort4 o;
    o.x = f2bf(v.x); o.y = f2bf(v.y); o.z = f2bf(v.z); o.w = f2bf(v.w);
    xb[i] = o;
}

// ---------------- kernel 2: W' = bf16(W + 2 * B @ A) ----------------
__global__ void fold_w_kernel(const float* __restrict__ W,
                              const float* __restrict__ lA,
                              const float* __restrict__ lB,
                              ushort* __restrict__ Wb) {
    int o  = blockIdx.y;
    int i0 = (blockIdx.x * blockDim.x + threadIdx.x) * 4;
    __shared__ float sB[RNK];
    if (threadIdx.x < RNK) sB[threadIdx.x] = lB[(size_t)o * RNK + threadIdx.x];
    __syncthreads();
    float4 w = *(const float4*)(W + (size_t)o * DIN + i0);
    float ax = 0.f, ay = 0.f, az = 0.f, aw = 0.f;
#pragma unroll
    for (int r = 0; r < RNK; r++) {
        float4 a = *(const float4*)(lA + (size_t)r * DIN + i0);
        float b = sB[r];
        ax += b * a.x; ay += b * a.y; az += b * a.z; aw += b * a.w;
    }
    ushort4 outv;
    outv.x = f2bf(w.x + LORA_SCALE * ax);
    outv.y = f2bf(w.y + LORA_SCALE * ay);
    outv.z = f2bf(w.z + LORA_SCALE * az);
    outv.w = f2bf(w.w + LORA_SCALE * aw);
    *(ushort4*)(Wb + (size_t)o * DIN + i0) = outv;
}

// ---------------- kernel 3: Y = Xb @ Wb^T + bias (128x128 tile, XOR-swizzled LDS) ----------------
// LDS layout: row-major [128][32] bf16, but chunk h (8 bf16) of row r is stored at
// chunk position p = h ^ ((r>>1)&3).  2-way banking on fragment reads (free, m136).
#define BM 128
#define BN 128
#define BK 32

__global__ __launch_bounds__(256) void gemm_bias_kernel(
    const ushort* __restrict__ Xb, const ushort* __restrict__ Wb,
    const float* __restrict__ bias, float* __restrict__ Y) {
    const int N = DOUT, K = DIN;
    __shared__ ushort sA[BM * BK];  // 8 KB
    __shared__ ushort sB[BN * BK];  // 8 KB

    const int tid  = threadIdx.x;
    const int lane = tid & 63;
    const int wave = tid >> 6;
    const int m0 = blockIdx.y * BM;
    const int n0 = blockIdx.x * BN;

    const int wave_m = wave & 1;
    const int wave_n = wave >> 1;
    const int wm64 = wave_m * 64;
    const int wn64 = wave_n * 64;

    // staging: thread t writes 16 B to LDS byte offset t*16 (wave-uniform + lane*16).
    // Global source is XOR-swizzled so LDS chunk position p of row r holds global chunk p^((r>>1)&3).
    const int srow = tid >> 2;                       // 0..63
    const int sw   = (srow >> 1) & 3;                // swizzle key (same for row srow and srow+64)
    const int scol = ((tid & 3) ^ sw) * 8;           // global chunk (bf16 elements)
    const ushort* ga0 = Xb + (size_t)(m0 + srow) * K + scol;
    const ushort* ga1 = Xb + (size_t)(m0 + 64 + srow) * K + scol;
    const ushort* gb0 = Wb + (size_t)(n0 + srow) * K + scol;
    const ushort* gb1 = Wb + (size_t)(n0 + 64 + srow) * K + scol;
    ushort* la0 = &sA[tid * 8];
    ushort* la1 = &sA[tid * 8 + 2048];
    ushort* lb0 = &sB[tid * 8];
    ushort* lb1 = &sB[tid * 8 + 2048];

    // fragment read: lane needs global chunk h = lane>>4 of row (wm64 + t*16 + lr);
    // it lives at chunk position h ^ ((lr>>1)&3)  (wm64, t*16 are 0 mod swizzle period).
    const int lr   = lane & 15;
    const int h    = lane >> 4;
    const int cpos = (h ^ ((lr >> 1) & 3)) * 8;      // bf16 element offset within row

    f32x4 acc[4][4] = {};

    for (int k0 = 0; k0 < K; k0 += BK) {
        __syncthreads();
        async_copy16(ga0, la0);
        async_copy16(ga1, la1);
        async_copy16(gb0, lb0);
        async_copy16(gb1, lb1);
        ga0 += BK; ga1 += BK; gb0 += BK; gb1 += BK;
        __syncthreads();

        bf16x8 af[4], bfr[4];
#pragma unroll
        for (int t = 0; t < 4; t++) {
            af[t]  = *(const bf16x8*)(&sA[(wm64 + t * 16 + lr) * BK + cpos]);
            bfr[t] = *(const bf16x8*)(&sB[(wn64 + t * 16 + lr) * BK + cpos]);
        }
#pragma unroll
        for (int im = 0; im < 4; im++)
#pragma unroll
            for (int in = 0; in < 4; in++)
                acc[im][in] = __builtin_amdgcn_mfma_f32_16x16x32_bf16(
                    af[im], bfr[in], acc[im][in], 0, 0, 0);
    }

    // epilogue: C/D layout col(n)=lane&15, row(m)=(lane>>4)*4+reg  [m89/m91 verified]
    const int col  = lane & 15;
    const int qrow = (lane >> 4) * 4;
#pragma unroll
    for (int in = 0; in < 4; in++) {
        const int n = n0 + wn64 + in * 16 + col;
        const float bv = bias[n];
#pragma unroll
        for (int im = 0; im < 4; im++) {
            const int m = m0 + wm64 + im * 16 + qrow;
            float* yp = Y + (size_t)m * N + n;
            yp[0 * (size_t)N] = acc[im][in].x + bv;
            yp[1 * (size_t)N] = acc[im][in].y + bv;
            yp[2 * (size_t)N] = acc[im][in].z + bv;
            yp[3 * (size_t)N] = acc[im][in].w + bv;
        }
    }
}

extern "C" void kernel_launch(void* const* d_in, const int* in_sizes, int n_in,
                              void* d_out, int out_size, void* d_ws, size_t ws_size,
                              hipStream_t stream) {
    const float* x    = (const float*)d_in[0];
    const float* W    = (const float*)d_in[1];
    const float* bias = (const float*)d_in[2];
    const float* lA   = (const float*)d_in[3];
    const float* lB   = (const float*)d_in[4];
    float* Y = (float*)d_out;

    ushort* xb = (ushort*)d_ws;                       // 64 MB
    ushort* wb = xb + (size_t)TOKENS * DIN;           // +32 MB

    cast_x_kernel<<<(TOKENS * DIN / 4) / 256, 256, 0, stream>>>(
        (const float4*)x, (ushort4*)xb);
    fold_w_kernel<<<dim3(DIN / (256 * 4), DOUT), 256, 0, stream>>>(W, lA, lB, wb);
    gemm_bias_kernel<<<dim3(DOUT / BN, TOKENS / BM), 256, 0, stream>>>(xb, wb, bias, Y);
}

// Round 3
// 602.960 us; speedup vs baseline: 1.0040x; 1.0040x over previous
//
#include <hip/hip_runtime.h>
#include <hip/hip_bf16.h>
#include <stdint.h>

#define TOKENS 8192
#define DIN 4096
#define DOUT 4096
#define RNK 16
#define LORA_SCALE 2.0f

typedef __attribute__((ext_vector_type(8))) __bf16 bf16x8;
typedef __attribute__((ext_vector_type(4))) float f32x4;

__device__ __forceinline__ unsigned short f2bf(float f) {
    union { float f; unsigned int u; } v; v.f = f;
    unsigned int u = v.u;
    unsigned int r = (u + 0x7fffu + ((u >> 16) & 1u)) >> 16;  // RNE
    return (unsigned short)r;
}

__device__ __forceinline__ void async_copy16(const void* g, void* l) {
    __builtin_amdgcn_global_load_lds(
        (const __attribute__((address_space(1))) void*)g,
        (__attribute__((address_space(3))) void*)l,
        16, 0, 0);
}

// ---------------- kernel 1: cast x (fp32) -> bf16 ----------------
__global__ void cast_x_kernel(const float4* __restrict__ x, ushort4* __restrict__ xb) {
    int i = blockIdx.x * blockDim.x + threadIdx.x;
    float4 v = x[i];
    ushort4 o;
    o.x = f2bf(v.x); o.y = f2bf(v.y); o.z = f2bf(v.z); o.w = f2bf(v.w);
    xb[i] = o;
}

// ---------------- kernel 2: W' = bf16(W + 2 * B @ A) ----------------
__global__ void fold_w_kernel(const float* __restrict__ W,
                              const float* __restrict__ lA,
                              const float* __restrict__ lB,
                              ushort* __restrict__ Wb) {
    int o  = blockIdx.y;
    int i0 = (blockIdx.x * blockDim.x + threadIdx.x) * 4;
    __shared__ float sB[RNK];
    if (threadIdx.x < RNK) sB[threadIdx.x] = lB[(size_t)o * RNK + threadIdx.x];
    __syncthreads();
    float4 w = *(const float4*)(W + (size_t)o * DIN + i0);
    float ax = 0.f, ay = 0.f, az = 0.f, aw = 0.f;
#pragma unroll
    for (int r = 0; r < RNK; r++) {
        float4 a = *(const float4*)(lA + (size_t)r * DIN + i0);
        float b = sB[r];
        ax += b * a.x; ay += b * a.y; az += b * a.z; aw += b * a.w;
    }
    ushort4 outv;
    outv.x = f2bf(w.x + LORA_SCALE * ax);
    outv.y = f2bf(w.y + LORA_SCALE * ay);
    outv.z = f2bf(w.z + LORA_SCALE * az);
    outv.w = f2bf(w.w + LORA_SCALE * aw);
    *(ushort4*)(Wb + (size_t)o * DIN + i0) = outv;
}

// ---------------- kernel 3: Y = Xb @ Wb^T + bias (128x128 tile, BK=64, XOR-swizzled LDS) ----------------
// LDS row = 64 bf16 = 128 B = 8 chunks of 16 B. Chunk g of row r stored at position g^(r&7).
// Fragment reads then hit all 8 bank-quads 2x over 16 lanes -> conflict-free (m136: 2-way is free).
#define BM 128
#define BN 128
#define BK 64

__global__ __launch_bounds__(256) void gemm_bias_kernel(
    const ushort* __restrict__ Xb, const ushort* __restrict__ Wb,
    const float* __restrict__ bias, float* __restrict__ Y) {
    const int N = DOUT, K = DIN;
    __shared__ ushort sA[BM * BK];  // 16 KB
    __shared__ ushort sB[BN * BK];  // 16 KB  (32 KB total -> 5 blocks/CU LDS bound)

    const int tid  = threadIdx.x;
    const int lane = tid & 63;
    const int wave = tid >> 6;
    const int m0 = blockIdx.y * BM;
    const int n0 = blockIdx.x * BN;

    const int wm64 = (wave & 1) * 64;
    const int wn64 = (wave >> 1) * 64;

    // staging: 256 threads cover 32 rows x 8 chunks per round; 4 rounds cover 128 rows.
    // Thread t has LDS chunk position p=(t&7) of row srow=(t>>3); it fetches global chunk p^(srow&7).
    const int srow = tid >> 3;                        // 0..31
    const int p    = tid & 7;
    const int scol = (p ^ (srow & 7)) * 8;            // global chunk, bf16 elements
    const ushort* gA = Xb + (size_t)(m0 + srow) * K + scol;
    const ushort* gB = Wb + (size_t)(n0 + srow) * K + scol;
    ushort* lAp = &sA[tid * 8];                       // round j adds j*2048 elements (j*32 rows)
    ushort* lBp = &sB[tid * 8];

    // fragment read: lane (lr,q) wants global chunk hg=(s<<2)|q of row r=wm64+t*16+lr.
    // It lives at chunk position hg^(r&7); r&7 == lr&7 (wm64,t*16 are 0 mod 8).
    const int lr  = lane & 15;
    const int q   = lane >> 4;
    const int swc = lr & 7;
    const int c0  = ((0 * 4 + q) ^ swc) * 8;          // element offset for k-sub 0
    const int c1  = ((1 * 4 + q) ^ swc) * 8;          // element offset for k-sub 1

    f32x4 acc[4][4] = {};

    for (int k0 = 0; k0 < K; k0 += BK) {
        __syncthreads();
#pragma unroll
        for (int j = 0; j < 4; j++) {
            async_copy16(gA + (size_t)(j * 32) * K, lAp + j * 2048);
            async_copy16(gB + (size_t)(j * 32) * K, lBp + j * 2048);
        }
        gA += BK; gB += BK;
        __syncthreads();

#pragma unroll
        for (int s = 0; s < 2; s++) {
            const int cs = s ? c1 : c0;
            bf16x8 af[4], bfr[4];
#pragma unroll
            for (int t = 0; t < 4; t++) {
                af[t]  = *(const bf16x8*)(&sA[(wm64 + t * 16 + lr) * BK + cs]);
                bfr[t] = *(const bf16x8*)(&sB[(wn64 + t * 16 + lr) * BK + cs]);
            }
#pragma unroll
            for (int im = 0; im < 4; im++)
#pragma unroll
                for (int in = 0; in < 4; in++)
                    acc[im][in] = __builtin_amdgcn_mfma_f32_16x16x32_bf16(
                        af[im], bfr[in], acc[im][in], 0, 0, 0);
        }
    }

    // epilogue: C/D layout col(n)=lane&15, row(m)=(lane>>4)*4+reg  [m89/m91 verified]
    const int col  = lane & 15;
    const int qrow = (lane >> 4) * 4;
#pragma unroll
    for (int in = 0; in < 4; in++) {
        const int n = n0 + wn64 + in * 16 + col;
        const float bv = bias[n];
#pragma unroll
        for (int im = 0; im < 4; im++) {
            const int m = m0 + wm64 + im * 16 + qrow;
            float* yp = Y + (size_t)m * N + n;
            yp[0 * (size_t)N] = acc[im][in].x + bv;
            yp[1 * (size_t)N] = acc[im][in].y + bv;
            yp[2 * (size_t)N] = acc[im][in].z + bv;
            yp[3 * (size_t)N] = acc[im][in].w + bv;
        }
    }
}

extern "C" void kernel_launch(void* const* d_in, const int* in_sizes, int n_in,
                              void* d_out, int out_size, void* d_ws, size_t ws_size,
                              hipStream_t stream) {
    const float* x    = (const float*)d_in[0];
    const float* W    = (const float*)d_in[1];
    const float* bias = (const float*)d_in[2];
    const float* lA   = (const float*)d_in[3];
    const float* lB   = (const float*)d_in[4];
    float* Y = (float*)d_out;

    ushort* xb = (ushort*)d_ws;                       // 64 MB
    ushort* wb = xb + (size_t)TOKENS * DIN;           // +32 MB

    cast_x_kernel<<<(TOKENS * DIN / 4) / 256, 256, 0, stream>>>(
        (const float4*)x, (ushort4*)xb);
    fold_w_kernel<<<dim3(DIN / (256 * 4), DOUT), 256, 0, stream>>>(W, lA, lB, wb);
    gemm_bias_kernel<<<dim3(DOUT / BN, TOKENS / BM), 256, 0, stream>>>(xb, wb, bias, Y);
}